// Round 13
// baseline (219.505 us; speedup 1.0000x reference)
//
#include <hip/hip_runtime.h>
#include <math.h>

// Problem constants
#define N_SP 96      // NV + NH
#define D_EMB 32
#define H_MLP 32
#define NPAIR 9216   // N*N
#define NBT 512      // B*T
#define HROWS 24     // rows per block (4 blocks per (b,t))

// float workspace offsets (floats)
#define WS_F_EMBI  0         // 96*32 (includes +b1)
#define WS_F_EMBJT 3072      // 32*97 (transposed [u][j], row stride 97)
#define WS_F_ALPHA 6176      // 96
#define WS_F_WG4   6272      // 9216*4  (forms 0-3, interleaved float4 per pair)
#define WS_F_WG1   43136     // 9216    (form 4 coef)

typedef __attribute__((ext_vector_type(8))) short bf16x8;
typedef __attribute__((ext_vector_type(4))) float f32x4;

// Fast gelu (tanh form) via v_exp_f32 + v_rcp_f32 (~3e-4 abs dev; msgs path only)
__device__ __forceinline__ float gelu_fast(float x){
  float x2 = x * x;
  float z  = x * fmaf(x2, -0.1029438824f, -2.3022077325f);
  float e  = __builtin_amdgcn_exp2f(z);
  return x * __builtin_amdgcn_rcpf(1.0f + e);
}

__device__ __forceinline__ unsigned short f2bf(float f){
  unsigned u = __builtin_bit_cast(unsigned, f);
  unsigned r = (u + 0x7FFFu + ((u >> 16) & 1u)) >> 16;
  return (unsigned short)r;
}
__device__ __forceinline__ float bf2f(unsigned short s){
  unsigned u = ((unsigned)s) << 16;
  return __builtin_bit_cast(float, u);
}

// ---- precompute: emb_i(+b1), emb_jT (stride 97), alpha ----
__global__ void pre1_kernel(const float* __restrict__ emb,
                            const float* __restrict__ w1, const float* __restrict__ b1,
                            const float* __restrict__ har,
                            float* __restrict__ wsf){
  const int n = blockIdx.x;
  const int t = threadIdx.x;           // 64 threads
  const int which = t >> 5, idx = t & 31;
  const float* e = emb + n * D_EMB;
  if (which == 0){
    float acc = b1[idx];
    #pragma unroll
    for (int u = 0; u < D_EMB; u++) acc = fmaf(e[u], w1[(2+u)*H_MLP + idx], acc);
    wsf[WS_F_EMBI + n*H_MLP + idx] = acc;
  } else {
    float acc = 0.f;
    #pragma unroll
    for (int u = 0; u < D_EMB; u++) acc = fmaf(e[u], w1[(2+D_EMB+u)*H_MLP + idx], acc);
    wsf[WS_F_EMBJT + idx*97 + n] = acc;   // transposed store [u][j], stride 97
  }
  if (t == 0){
    float h = har[n];
    float sp = (h > 20.f) ? h : log1pf(expf(h));
    wsf[WS_F_ALPHA + n] = sp + 0.01f;
  }
}

// ---- precompute wg = form_coefs * sigmoid(gates), repacked ----
__global__ void prewg_kernel(const float* __restrict__ fc, const float* __restrict__ fg,
                             float* __restrict__ wsf){
  int idx = blockIdx.x * 256 + threadIdx.x;
  if (idx < 5 * NPAIR){
    float g = 1.f / (1.f + expf(-fg[idx]));
    float v = fc[idx] * g;
    int f = idx / NPAIR;
    int p = idx - f * NPAIR;
    if (f < 4) wsf[WS_F_WG4 + 4*p + f] = v;
    else       wsf[WS_F_WG1 + p] = v;
  }
}

// Emulate numpy einsum f32 dot (SSE baseline, mul+add, 4x unroll, ascending
// chain), horizontal (acc0+acc1)+(acc2+acc3), then f32 division by sqrt(32).
// DO NOT TOUCH arithmetic — bit-matched to the np reference (topk razor rows).
__device__ __forceinline__ float np_score(const float* __restrict__ qi,
                                          const float* __restrict__ kT, int j){
  float acc[4];
  #pragma unroll
  for (int l = 0; l < 4; l++){
    float t = __fadd_rn(__fmul_rn(qi[4+l],  kT[(4+l)*97 + j]),
                        __fmul_rn(qi[l],    kT[(l)*97 + j]));
    t = __fadd_rn(__fmul_rn(qi[8+l],  kT[(8+l)*97 + j]), t);
    t = __fadd_rn(__fmul_rn(qi[12+l], kT[(12+l)*97 + j]), t);
    t = __fadd_rn(__fmul_rn(qi[16+l], kT[(16+l)*97 + j]), t);
    t = __fadd_rn(__fmul_rn(qi[20+l], kT[(20+l)*97 + j]), t);
    t = __fadd_rn(__fmul_rn(qi[24+l], kT[(24+l)*97 + j]), t);
    t = __fadd_rn(__fmul_rn(qi[28+l], kT[(28+l)*97 + j]), t);
    acc[l] = t;
  }
  float s01 = __fadd_rn(acc[0], acc[1]);
  float s23 = __fadd_rn(acc[2], acc[3]);
  return __fdiv_rn(__fadd_rn(s01, s23), 5.65685424949238019521f);
}

// ---- main: 4 blocks per (b,t); block owns 24 rows; msgs staged in LDS bf16 ----
// 36 KB LDS -> 3 blocks/CU at VGPR 72 (occupancy lever vs R12's 56.8 KB / 2).
__global__ __launch_bounds__(512, 6) void main_kernel(
    const float* __restrict__ state, const float* __restrict__ rvec,
    const float* __restrict__ emb,
    const float* __restrict__ qwg, const float* __restrict__ qbg,
    const float* __restrict__ kwg, const float* __restrict__ kbg,
    const float* __restrict__ w1, const float* __restrict__ w2g,
    const float* __restrict__ b2g, const float* __restrict__ w3g,
    const float* __restrict__ b3g,
    const float* __restrict__ wsf,
    float* __restrict__ out_lr, float* __restrict__ out_attn){

  __shared__ __align__(16) float s_embi[HROWS*H_MLP];   // own rows only (3 KB)
  __shared__ float s_embjT[H_MLP*97];                   // 12.4 KB
  __shared__ __align__(16) float s_q[HROWS*D_EMB];      // 3 KB
  __shared__ float s_kT[D_EMB*97];                      // 12.4 KB
  __shared__ unsigned short s_ms[HROWS*N_SP];           // msgs staging, bf16 (4.6 KB)
  __shared__ float s_x[N_SP], s_hol[N_SP];
  __shared__ float s_wxi[H_MLP], s_wxj[H_MLP], s_b2[H_MLP], s_w3[H_MLP];

  const int tid  = threadIdx.x;
  const int bt   = blockIdx.x >> 2;
  const int roff = (blockIdx.x & 3) * HROWS;
  const int wave = tid >> 6, lane = tid & 63;

  for (int idx = tid; idx < HROWS*H_MLP; idx += 512)
    s_embi[idx] = wsf[WS_F_EMBI + roff*H_MLP + idx];
  for (int idx = tid; idx < H_MLP*97; idx += 512)
    s_embjT[idx] = wsf[WS_F_EMBJT + idx];
  if (tid < N_SP){
    float x = state[bt*N_SP + tid];
    s_x[tid] = x;
    float al = wsf[WS_F_ALPHA + tid];
    s_hol[tid] = x / (1.f + al * x);
  }
  if (tid >= 128 && tid < 160){
    int u = tid - 128;
    s_wxi[u] = w1[u];
    s_wxj[u] = w1[H_MLP + u];
    s_b2[u]  = b2g[u];
    s_w3[u]  = w3g[u];
  }
  __syncthreads();

  // Phase 0 (bit-exact feed of scores): kT for ALL n; q for own rows.
  for (int t = tid; t < N_SP*D_EMB; t += 512){
    const int n = t >> 5, d2 = t & 31;
    const float* e = emb + n*D_EMB;
    float ak = __fmul_rn(s_x[n], kwg[d2]);
    #pragma unroll
    for (int u = 0; u < D_EMB; u++)
      ak = fmaf(e[u], kwg[(1+u)*D_EMB + d2], ak);
    ak = __fadd_rn(ak, kbg[d2]);
    s_kT[d2*97 + n] = ak;
  }
  for (int t = tid; t < HROWS*D_EMB; t += 512){
    const int nl = t >> 5, d2 = t & 31;
    const int n  = roff + nl;
    const float* e = emb + n*D_EMB;
    float aq = __fmul_rn(s_x[n], qwg[d2]);
    #pragma unroll
    for (int u = 0; u < D_EMB; u++)
      aq = fmaf(e[u], qwg[(1+u)*D_EMB + d2], aq);
    aq = __fadd_rn(aq, qbg[d2]);
    s_q[t] = aq;
  }

  const float b3v = b3g[0];
  const float* wg4 = wsf + WS_F_WG4;
  const float* wg1 = wsf + WS_F_WG1;

  // w2^T as MFMA A-operand fragments. A[row=unit l15][k=kb+e] = w2[k][unit].
  const int l15 = lane & 15;
  const int g16 = lane >> 4;
  const int kb  = g16 * 8;
  bf16x8 w2f0, w2f1;
  #pragma unroll
  for (int e = 0; e < 8; e++){
    w2f0[e] = (short)f2bf(w2g[(kb+e)*H_MLP + l15]);
    w2f1[e] = (short)f2bf(w2g[(kb+e)*H_MLP + 16 + l15]);
  }
  float b2a[4], b2b[4], w3a[4], w3b[4];
  #pragma unroll
  for (int r = 0; r < 4; r++){
    b2a[r] = s_b2[4*g16 + r];      b2b[r] = s_b2[16 + 4*g16 + r];
    w3a[r] = s_w3[4*g16 + r];      w3b[r] = s_w3[16 + 4*g16 + r];
  }
  float wi[8], wj[8];
  #pragma unroll
  for (int e = 0; e < 8; e++){ wi[e] = s_wxi[kb+e]; wj[e] = s_wxj[kb+e]; }
  __syncthreads();   // phase-0 stores visible

  // Phase 1: msgs via transposed-MFMA pairwise MLP -> LDS (bf16). 3 rows/wave.
  for (int ii = 0; ii < 3; ii++){
    const int il = 3*wave + ii;          // local row 0..23
    const int i  = roff + il;
    const float xi = s_x[i];
    float base[8];
    #pragma unroll
    for (int e = 0; e < 8; e++)
      base[e] = fmaf(xi, wi[e], s_embi[il*H_MLP + kb + e]);

    for (int jb = 0; jb < 6; jb++){
      const int j0 = 16*jb;
      const int jl = j0 + l15;
      const float xj = s_x[jl];

      // early loads for the msg tail (hide global latency under MFMA)
      float4 w4v = {0,0,0,0};
      float  w1v = 0.f, xjp = 0.f, hjp = 0.f;
      if (lane < 16){
        const int p = i*N_SP + j0 + lane;
        w4v = *(const float4*)&wg4[4*p];
        w1v = wg1[p];
        xjp = s_x[j0 + lane];
        hjp = s_hol[j0 + lane];
      }

      // h1 fragment (B-operand): lane holds h1[pair=l15][k=kb+e]
      bf16x8 hfrag;
      #pragma unroll
      for (int e = 0; e < 8; e++){
        float pre = fmaf(xj, wj[e], base[e] + s_embjT[(kb+e)*97 + jl]);
        hfrag[e] = (short)f2bf(gelu_fast(pre));
      }

      f32x4 acc0 = {b2a[0], b2a[1], b2a[2], b2a[3]};
      f32x4 acc1 = {b2b[0], b2b[1], b2b[2], b2b[3]};
      acc0 = __builtin_amdgcn_mfma_f32_16x16x32_bf16(w2f0, hfrag, acc0, 0, 0, 0);
      acc1 = __builtin_amdgcn_mfma_f32_16x16x32_bf16(w2f1, hfrag, acc1, 0, 0, 0);

      float part = 0.f;
      #pragma unroll
      for (int r = 0; r < 4; r++) part = fmaf(gelu_fast(acc0[r]), w3a[r], part);
      #pragma unroll
      for (int r = 0; r < 4; r++) part = fmaf(gelu_fast(acc1[r]), w3b[r], part);
      part += __shfl_xor(part, 16);
      part += __shfl_xor(part, 32);

      if (lane < 16){
        const float f4 = part + b3v;
        const float msg = w4v.x * xjp
                        + w4v.y * (xi*xjp)
                        + w4v.z * hjp
                        + w4v.w * (xi*hjp)
                        + w1v   * f4;
        s_ms[il*N_SP + j0 + lane] = f2bf(msg);
      }
    }
  }
  __syncthreads();   // s_ms visible across waves

  // Phase 2: np-exact scores -> radix-select exact 8th-largest threshold ->
  // softmax normalized by threshold (ratio-invariant) -> aggregate.
  const float LOG2E = 1.44269504088896340736f;

  for (int ip = 0; ip < 3; ip++){
    const int il2 = wave + 8*ip;         // local row 0..23
    const int i   = roff + il2;
    const float* qi = s_q + il2*D_EMB;
    float v0 = np_score(qi, s_kT, lane);
    float v1 = 0.f;
    if (lane < 32) v1 = np_score(qi, s_kT, 64 + lane);

    unsigned k0 = __builtin_bit_cast(unsigned, v0);
    k0 = (k0 >> 31) ? ~k0 : (k0 | 0x80000000u);
    unsigned k1 = 0u;
    if (lane < 32){
      unsigned u1 = __builtin_bit_cast(unsigned, v1);
      k1 = (u1 >> 31) ? ~u1 : (u1 | 0x80000000u);
    }

    // exact 8th-largest key via 32-step binary search on bits
    unsigned T = 0u;
    #pragma unroll
    for (int b = 31; b >= 0; --b){
      unsigned Tc = T | (1u << b);
      unsigned long long mm0 = __ballot(k0 >= Tc);
      unsigned long long mm1 = __ballot(k1 >= Tc);
      int cnt = __popcll(mm0) + __popcll(mm1);
      if (cnt >= 8) T = Tc;
    }
    unsigned uth = (T >> 31) ? (T ^ 0x80000000u) : ~T;
    const float thrf = __builtin_bit_cast(float, uth);

    float e0 = (k0 >= T) ? __builtin_amdgcn_exp2f(LOG2E*(v0 - thrf)) : 0.f;
    float e1 = 0.f;
    if (lane < 32 && k1 >= T) e1 = __builtin_amdgcn_exp2f(LOG2E*(v1 - thrf));

    const unsigned short* srow = s_ms + il2*N_SP;
    float num = e0 * bf2f(srow[lane]);
    if (lane < 32) num += e1 * bf2f(srow[64 + lane]);
    float den = e0 + e1;
    #pragma unroll
    for (int off = 32; off; off >>= 1){
      den += __shfl_xor(den, off);
      num += __shfl_xor(num, off);
    }
    float inv = 1.0f / den;
    float* arow = out_attn + (size_t)(bt*N_SP + i) * N_SP;
    arow[lane] = e0 * inv;
    if (lane < 32) arow[64 + lane] = e1 * inv;
    if (lane == 0) out_lr[bt*N_SP + i] = rvec[i] + num * inv;
  }
}

extern "C" void kernel_launch(void* const* d_in, const int* in_sizes, int n_in,
                              void* d_out, int out_size, void* d_ws, size_t ws_size,
                              hipStream_t stream){
  const float* state = (const float*)d_in[0];
  const float* emb   = (const float*)d_in[1];
  const float* qw    = (const float*)d_in[2];
  const float* qb    = (const float*)d_in[3];
  const float* kw    = (const float*)d_in[4];
  const float* kb    = (const float*)d_in[5];
  const float* fc    = (const float*)d_in[6];
  const float* fg    = (const float*)d_in[7];
  const float* har   = (const float*)d_in[8];
  const float* w1    = (const float*)d_in[9];
  const float* b1    = (const float*)d_in[10];
  const float* w2    = (const float*)d_in[11];
  const float* b2    = (const float*)d_in[12];
  const float* w3    = (const float*)d_in[13];
  const float* b3    = (const float*)d_in[14];
  const float* rv    = (const float*)d_in[15];

  float* wsf = (float*)d_ws;
  float* out_lr   = (float*)d_out;
  float* out_attn = out_lr + NBT * N_SP;

  hipLaunchKernelGGL(pre1_kernel, dim3(N_SP), dim3(64), 0, stream,
                     emb, w1, b1, har, wsf);
  hipLaunchKernelGGL(prewg_kernel, dim3(180), dim3(256), 0, stream, fc, fg, wsf);
  hipLaunchKernelGGL(main_kernel, dim3(4*NBT), dim3(512), 0, stream,
                     state, rv, emb, qw, qb, kw, kb, w1, w2, b2, w3, b3,
                     wsf, out_lr, out_attn);
}

// Round 14
// 200.755 us; speedup vs baseline: 1.0934x; 1.0934x over previous
//
#include <hip/hip_runtime.h>
#include <math.h>

// Problem constants
#define N_SP 96      // NV + NH
#define D_EMB 32
#define H_MLP 32
#define NPAIR 9216   // N*N
#define NBT 512      // B*T
#define HROWS 24     // rows per block (4 blocks per (b,t))

// float workspace offsets (floats)
#define WS_F_EMBI  0         // 96*32 (includes +b1)
#define WS_F_EMBJT 3072      // 32*97 (transposed [u][j], row stride 97)
#define WS_F_ALPHA 6176      // 96
#define WS_F_WG4   6272      // 9216*4  (forms 0-3, interleaved float4 per pair)
#define WS_F_WG1   43136     // 9216    (form 4 coef)

typedef __attribute__((ext_vector_type(8))) short bf16x8;
typedef __attribute__((ext_vector_type(4))) float f32x4;

// Fast gelu (tanh form) via v_exp_f32 + v_rcp_f32 (~3e-4 abs dev; msgs path only)
__device__ __forceinline__ float gelu_fast(float x){
  float x2 = x * x;
  float z  = x * fmaf(x2, -0.1029438824f, -2.3022077325f);
  float e  = __builtin_amdgcn_exp2f(z);
  return x * __builtin_amdgcn_rcpf(1.0f + e);
}

__device__ __forceinline__ unsigned short f2bf(float f){
  unsigned u = __builtin_bit_cast(unsigned, f);
  unsigned r = (u + 0x7FFFu + ((u >> 16) & 1u)) >> 16;
  return (unsigned short)r;
}

// ---- precompute: emb_i(+b1), emb_jT (stride 97), alpha ----
__global__ void pre1_kernel(const float* __restrict__ emb,
                            const float* __restrict__ w1, const float* __restrict__ b1,
                            const float* __restrict__ har,
                            float* __restrict__ wsf){
  const int n = blockIdx.x;
  const int t = threadIdx.x;           // 64 threads
  const int which = t >> 5, idx = t & 31;
  const float* e = emb + n * D_EMB;
  if (which == 0){
    float acc = b1[idx];
    #pragma unroll
    for (int u = 0; u < D_EMB; u++) acc = fmaf(e[u], w1[(2+u)*H_MLP + idx], acc);
    wsf[WS_F_EMBI + n*H_MLP + idx] = acc;
  } else {
    float acc = 0.f;
    #pragma unroll
    for (int u = 0; u < D_EMB; u++) acc = fmaf(e[u], w1[(2+D_EMB+u)*H_MLP + idx], acc);
    wsf[WS_F_EMBJT + idx*97 + n] = acc;   // transposed store [u][j], stride 97
  }
  if (t == 0){
    float h = har[n];
    float sp = (h > 20.f) ? h : log1pf(expf(h));
    wsf[WS_F_ALPHA + n] = sp + 0.01f;
  }
}

// ---- precompute wg = form_coefs * sigmoid(gates), repacked ----
__global__ void prewg_kernel(const float* __restrict__ fc, const float* __restrict__ fg,
                             float* __restrict__ wsf){
  int idx = blockIdx.x * 256 + threadIdx.x;
  if (idx < 5 * NPAIR){
    float g = 1.f / (1.f + expf(-fg[idx]));
    float v = fc[idx] * g;
    int f = idx / NPAIR;
    int p = idx - f * NPAIR;
    if (f < 4) wsf[WS_F_WG4 + 4*p + f] = v;
    else       wsf[WS_F_WG1 + p] = v;
  }
}

// Emulate numpy einsum f32 dot (SSE baseline, mul+add, 4x unroll, ascending
// chain), horizontal (acc0+acc1)+(acc2+acc3), then f32 division by sqrt(32).
// DO NOT TOUCH arithmetic — bit-matched to the np reference (topk razor rows).
__device__ __forceinline__ float np_score(const float* __restrict__ qi,
                                          const float* __restrict__ kT, int j){
  float acc[4];
  #pragma unroll
  for (int l = 0; l < 4; l++){
    float t = __fadd_rn(__fmul_rn(qi[4+l],  kT[(4+l)*97 + j]),
                        __fmul_rn(qi[l],    kT[(l)*97 + j]));
    t = __fadd_rn(__fmul_rn(qi[8+l],  kT[(8+l)*97 + j]), t);
    t = __fadd_rn(__fmul_rn(qi[12+l], kT[(12+l)*97 + j]), t);
    t = __fadd_rn(__fmul_rn(qi[16+l], kT[(16+l)*97 + j]), t);
    t = __fadd_rn(__fmul_rn(qi[20+l], kT[(20+l)*97 + j]), t);
    t = __fadd_rn(__fmul_rn(qi[24+l], kT[(24+l)*97 + j]), t);
    t = __fadd_rn(__fmul_rn(qi[28+l], kT[(28+l)*97 + j]), t);
    acc[l] = t;
  }
  float s01 = __fadd_rn(acc[0], acc[1]);
  float s23 = __fadd_rn(acc[2], acc[3]);
  return __fdiv_rn(__fadd_rn(s01, s23), 5.65685424949238019521f);
}

// ---- main: 4 blocks per (b,t); block owns 24 rows; msgs staged in LDS f32 ----
// LDS 41.5 KB deliberately in (40, 53.3] KB: caps residency at 3 blocks/CU so
// the compiler's occupancy heuristic targets 6 waves/EU (VGPR budget 85) and
// does NOT squeeze the register file (R13: 36.9 KB -> 4-block target -> VGPR 40
// -> 268 MB scratch spill. R12: same code at 2 blocks -> VGPR 72, spill-free).
__global__ __launch_bounds__(512, 6) void main_kernel(
    const float* __restrict__ state, const float* __restrict__ rvec,
    const float* __restrict__ emb,
    const float* __restrict__ qwg, const float* __restrict__ qbg,
    const float* __restrict__ kwg, const float* __restrict__ kbg,
    const float* __restrict__ w1, const float* __restrict__ w2g,
    const float* __restrict__ b2g, const float* __restrict__ w3g,
    const float* __restrict__ b3g,
    const float* __restrict__ wsf,
    float* __restrict__ out_lr, float* __restrict__ out_attn){

  __shared__ __align__(16) float s_embi[HROWS*H_MLP];   // 3 KB
  __shared__ float s_embjT[H_MLP*97];                   // 12.4 KB
  __shared__ __align__(16) float s_q[HROWS*D_EMB];      // 3 KB
  __shared__ float s_kT[D_EMB*97];                      // 12.4 KB
  __shared__ float s_ms[HROWS*N_SP];                    // msgs staging f32 (9.2 KB)
  __shared__ float s_x[N_SP], s_hol[N_SP];
  __shared__ float s_wxi[H_MLP], s_wxj[H_MLP], s_b2[H_MLP], s_w3[H_MLP];

  const int tid  = threadIdx.x;
  const int bt   = blockIdx.x >> 2;
  const int roff = (blockIdx.x & 3) * HROWS;
  const int wave = tid >> 6, lane = tid & 63;

  for (int idx = tid; idx < HROWS*H_MLP; idx += 512)
    s_embi[idx] = wsf[WS_F_EMBI + roff*H_MLP + idx];
  for (int idx = tid; idx < H_MLP*97; idx += 512)
    s_embjT[idx] = wsf[WS_F_EMBJT + idx];
  if (tid < N_SP){
    float x = state[bt*N_SP + tid];
    s_x[tid] = x;
    float al = wsf[WS_F_ALPHA + tid];
    s_hol[tid] = x / (1.f + al * x);
  }
  if (tid >= 128 && tid < 160){
    int u = tid - 128;
    s_wxi[u] = w1[u];
    s_wxj[u] = w1[H_MLP + u];
    s_b2[u]  = b2g[u];
    s_w3[u]  = w3g[u];
  }
  __syncthreads();

  // Phase 0 (bit-exact feed of scores): kT for ALL n; q for own rows.
  for (int t = tid; t < N_SP*D_EMB; t += 512){
    const int n = t >> 5, d2 = t & 31;
    const float* e = emb + n*D_EMB;
    float ak = __fmul_rn(s_x[n], kwg[d2]);
    #pragma unroll
    for (int u = 0; u < D_EMB; u++)
      ak = fmaf(e[u], kwg[(1+u)*D_EMB + d2], ak);
    ak = __fadd_rn(ak, kbg[d2]);
    s_kT[d2*97 + n] = ak;
  }
  for (int t = tid; t < HROWS*D_EMB; t += 512){
    const int nl = t >> 5, d2 = t & 31;
    const int n  = roff + nl;
    const float* e = emb + n*D_EMB;
    float aq = __fmul_rn(s_x[n], qwg[d2]);
    #pragma unroll
    for (int u = 0; u < D_EMB; u++)
      aq = fmaf(e[u], qwg[(1+u)*D_EMB + d2], aq);
    aq = __fadd_rn(aq, qbg[d2]);
    s_q[t] = aq;
  }

  const float b3v = b3g[0];
  const float* wg4 = wsf + WS_F_WG4;
  const float* wg1 = wsf + WS_F_WG1;

  // w2^T as MFMA A-operand fragments. A[row=unit l15][k=kb+e] = w2[k][unit].
  const int l15 = lane & 15;
  const int g16 = lane >> 4;
  const int kb  = g16 * 8;
  bf16x8 w2f0, w2f1;
  #pragma unroll
  for (int e = 0; e < 8; e++){
    w2f0[e] = (short)f2bf(w2g[(kb+e)*H_MLP + l15]);
    w2f1[e] = (short)f2bf(w2g[(kb+e)*H_MLP + 16 + l15]);
  }
  float b2a[4], b2b[4], w3a[4], w3b[4];
  #pragma unroll
  for (int r = 0; r < 4; r++){
    b2a[r] = s_b2[4*g16 + r];      b2b[r] = s_b2[16 + 4*g16 + r];
    w3a[r] = s_w3[4*g16 + r];      w3b[r] = s_w3[16 + 4*g16 + r];
  }
  float wi[8], wj[8];
  #pragma unroll
  for (int e = 0; e < 8; e++){ wi[e] = s_wxi[kb+e]; wj[e] = s_wxj[kb+e]; }
  __syncthreads();   // phase-0 stores visible

  // Phase 1: msgs via transposed-MFMA pairwise MLP -> LDS. 3 rows/wave.
  for (int ii = 0; ii < 3; ii++){
    const int il = 3*wave + ii;          // local row 0..23
    const int i  = roff + il;
    const float xi = s_x[i];
    float base[8];
    #pragma unroll
    for (int e = 0; e < 8; e++)
      base[e] = fmaf(xi, wi[e], s_embi[il*H_MLP + kb + e]);

    for (int jb = 0; jb < 6; jb++){
      const int j0 = 16*jb;
      const int jl = j0 + l15;
      const float xj = s_x[jl];

      // early loads for the msg tail (hide global latency under MFMA)
      float4 w4v = {0,0,0,0};
      float  w1v = 0.f, xjp = 0.f, hjp = 0.f;
      if (lane < 16){
        const int p = i*N_SP + j0 + lane;
        w4v = *(const float4*)&wg4[4*p];
        w1v = wg1[p];
        xjp = s_x[j0 + lane];
        hjp = s_hol[j0 + lane];
      }

      // h1 fragment (B-operand): lane holds h1[pair=l15][k=kb+e]
      bf16x8 hfrag;
      #pragma unroll
      for (int e = 0; e < 8; e++){
        float pre = fmaf(xj, wj[e], base[e] + s_embjT[(kb+e)*97 + jl]);
        hfrag[e] = (short)f2bf(gelu_fast(pre));
      }

      f32x4 acc0 = {b2a[0], b2a[1], b2a[2], b2a[3]};
      f32x4 acc1 = {b2b[0], b2b[1], b2b[2], b2b[3]};
      acc0 = __builtin_amdgcn_mfma_f32_16x16x32_bf16(w2f0, hfrag, acc0, 0, 0, 0);
      acc1 = __builtin_amdgcn_mfma_f32_16x16x32_bf16(w2f1, hfrag, acc1, 0, 0, 0);

      float part = 0.f;
      #pragma unroll
      for (int r = 0; r < 4; r++) part = fmaf(gelu_fast(acc0[r]), w3a[r], part);
      #pragma unroll
      for (int r = 0; r < 4; r++) part = fmaf(gelu_fast(acc1[r]), w3b[r], part);
      part += __shfl_xor(part, 16);
      part += __shfl_xor(part, 32);

      if (lane < 16){
        const float f4 = part + b3v;
        const float msg = w4v.x * xjp
                        + w4v.y * (xi*xjp)
                        + w4v.z * hjp
                        + w4v.w * (xi*hjp)
                        + w1v   * f4;
        s_ms[il*N_SP + j0 + lane] = msg;
      }
    }
  }
  __syncthreads();   // s_ms visible across waves

  // Phase 2: np-exact scores -> radix-select exact 8th-largest threshold ->
  // softmax normalized by threshold (ratio-invariant) -> aggregate.
  const float LOG2E = 1.44269504088896340736f;

  for (int ip = 0; ip < 3; ip++){
    const int il2 = wave + 8*ip;         // local row 0..23
    const int i   = roff + il2;
    const float* qi = s_q + il2*D_EMB;
    float v0 = np_score(qi, s_kT, lane);
    float v1 = 0.f;
    if (lane < 32) v1 = np_score(qi, s_kT, 64 + lane);

    unsigned k0 = __builtin_bit_cast(unsigned, v0);
    k0 = (k0 >> 31) ? ~k0 : (k0 | 0x80000000u);
    unsigned k1 = 0u;
    if (lane < 32){
      unsigned u1 = __builtin_bit_cast(unsigned, v1);
      k1 = (u1 >> 31) ? ~u1 : (u1 | 0x80000000u);
    }

    // exact 8th-largest key via 32-step binary search on bits
    unsigned T = 0u;
    #pragma unroll
    for (int b = 31; b >= 0; --b){
      unsigned Tc = T | (1u << b);
      unsigned long long mm0 = __ballot(k0 >= Tc);
      unsigned long long mm1 = __ballot(k1 >= Tc);
      int cnt = __popcll(mm0) + __popcll(mm1);
      if (cnt >= 8) T = Tc;
    }
    unsigned uth = (T >> 31) ? (T ^ 0x80000000u) : ~T;
    const float thrf = __builtin_bit_cast(float, uth);

    float e0 = (k0 >= T) ? __builtin_amdgcn_exp2f(LOG2E*(v0 - thrf)) : 0.f;
    float e1 = 0.f;
    if (lane < 32 && k1 >= T) e1 = __builtin_amdgcn_exp2f(LOG2E*(v1 - thrf));

    const float* srow = s_ms + il2*N_SP;
    float num = e0 * srow[lane];
    if (lane < 32) num += e1 * srow[64 + lane];
    float den = e0 + e1;
    #pragma unroll
    for (int off = 32; off; off >>= 1){
      den += __shfl_xor(den, off);
      num += __shfl_xor(num, off);
    }
    float inv = 1.0f / den;
    float* arow = out_attn + (size_t)(bt*N_SP + i) * N_SP;
    arow[lane] = e0 * inv;
    if (lane < 32) arow[64 + lane] = e1 * inv;
    if (lane == 0) out_lr[bt*N_SP + i] = rvec[i] + num * inv;
  }
}

extern "C" void kernel_launch(void* const* d_in, const int* in_sizes, int n_in,
                              void* d_out, int out_size, void* d_ws, size_t ws_size,
                              hipStream_t stream){
  const float* state = (const float*)d_in[0];
  const float* emb   = (const float*)d_in[1];
  const float* qw    = (const float*)d_in[2];
  const float* qb    = (const float*)d_in[3];
  const float* kw    = (const float*)d_in[4];
  const float* kb    = (const float*)d_in[5];
  const float* fc    = (const float*)d_in[6];
  const float* fg    = (const float*)d_in[7];
  const float* har   = (const float*)d_in[8];
  const float* w1    = (const float*)d_in[9];
  const float* b1    = (const float*)d_in[10];
  const float* w2    = (const float*)d_in[11];
  const float* b2    = (const float*)d_in[12];
  const float* w3    = (const float*)d_in[13];
  const float* b3    = (const float*)d_in[14];
  const float* rv    = (const float*)d_in[15];

  float* wsf = (float*)d_ws;
  float* out_lr   = (float*)d_out;
  float* out_attn = out_lr + NBT * N_SP;

  hipLaunchKernelGGL(pre1_kernel, dim3(N_SP), dim3(64), 0, stream,
                     emb, w1, b1, har, wsf);
  hipLaunchKernelGGL(prewg_kernel, dim3(180), dim3(256), 0, stream, fc, fg, wsf);
  hipLaunchKernelGGL(main_kernel, dim3(4*NBT), dim3(512), 0, stream,
                     state, rv, emb, qw, qb, kw, kb, w1, w2, b2, w3, b3,
                     wsf, out_lr, out_attn);
}

// Round 16
// 189.321 us; speedup vs baseline: 1.1594x; 1.0604x over previous
//
#include <hip/hip_runtime.h>
#include <math.h>

// Problem constants
#define N_SP 96      // NV + NH
#define D_EMB 32
#define H_MLP 32
#define NPAIR 9216   // N*N
#define NBT 512      // B*T
#define HROWS 48     // rows per block (2 blocks per (b,t))

// float workspace offsets (floats)
#define WS_F_EMBI  0         // 96*32 (includes +b1)
#define WS_F_EMBJT 3072      // 32*97 (transposed [u][j], row stride 97)
#define WS_F_ALPHA 6176      // 96
#define WS_F_WG4   6272      // 9216*4  (forms 0-3, interleaved float4 per pair)
#define WS_F_WG1   43136     // 9216    (form 4 coef)

typedef __attribute__((ext_vector_type(8))) short bf16x8;
typedef __attribute__((ext_vector_type(4))) float f32x4;
typedef __attribute__((ext_vector_type(4))) unsigned u32x4;

// Fast gelu (tanh form) via v_exp_f32 + v_rcp_f32 (~3e-4 abs dev; msgs path only)
__device__ __forceinline__ float gelu_fast(float x){
  float x2 = x * x;
  float z  = x * fmaf(x2, -0.1029438824f, -2.3022077325f);
  float e  = __builtin_amdgcn_exp2f(z);
  return x * __builtin_amdgcn_rcpf(1.0f + e);
}

__device__ __forceinline__ unsigned short f2bf(float f){
  unsigned u = __builtin_bit_cast(unsigned, f);
  unsigned r = (u + 0x7FFFu + ((u >> 16) & 1u)) >> 16;
  return (unsigned short)r;
}

// packed f32x2 -> bf16x2 (RNE) in one instruction; no builtin on gfx950 (m240)
__device__ __forceinline__ unsigned cvt_pk_bf16(float lo, float hi){
  unsigned r;
  asm("v_cvt_pk_bf16_f32 %0, %1, %2" : "=v"(r) : "v"(lo), "v"(hi));
  return r;
}

// ---- precompute: emb_i(+b1), emb_jT (stride 97), alpha ----
__global__ void pre1_kernel(const float* __restrict__ emb,
                            const float* __restrict__ w1, const float* __restrict__ b1,
                            const float* __restrict__ har,
                            float* __restrict__ wsf){
  const int n = blockIdx.x;
  const int t = threadIdx.x;           // 64 threads
  const int which = t >> 5, idx = t & 31;
  const float* e = emb + n * D_EMB;
  if (which == 0){
    float acc = b1[idx];
    #pragma unroll
    for (int u = 0; u < D_EMB; u++) acc = fmaf(e[u], w1[(2+u)*H_MLP + idx], acc);
    wsf[WS_F_EMBI + n*H_MLP + idx] = acc;
  } else {
    float acc = 0.f;
    #pragma unroll
    for (int u = 0; u < D_EMB; u++) acc = fmaf(e[u], w1[(2+D_EMB+u)*H_MLP + idx], acc);
    wsf[WS_F_EMBJT + idx*97 + n] = acc;   // transposed store [u][j], stride 97
  }
  if (t == 0){
    float h = har[n];
    float sp = (h > 20.f) ? h : log1pf(expf(h));
    wsf[WS_F_ALPHA + n] = sp + 0.01f;
  }
}

// ---- precompute wg = form_coefs * sigmoid(gates), repacked ----
__global__ void prewg_kernel(const float* __restrict__ fc, const float* __restrict__ fg,
                             float* __restrict__ wsf){
  int idx = blockIdx.x * 256 + threadIdx.x;
  if (idx < 5 * NPAIR){
    float g = 1.f / (1.f + expf(-fg[idx]));
    float v = fc[idx] * g;
    int f = idx / NPAIR;
    int p = idx - f * NPAIR;
    if (f < 4) wsf[WS_F_WG4 + 4*p + f] = v;
    else       wsf[WS_F_WG1 + p] = v;
  }
}

// Emulate numpy einsum f32 dot (SSE baseline, mul+add, 4x unroll, ascending
// chain), horizontal (acc0+acc1)+(acc2+acc3), then f32 division by sqrt(32).
// DO NOT TOUCH arithmetic — bit-matched to the np reference (topk razor rows).
__device__ __forceinline__ float np_score(const float* __restrict__ qi,
                                          const float* __restrict__ kT, int j){
  float acc[4];
  #pragma unroll
  for (int l = 0; l < 4; l++){
    float t = __fadd_rn(__fmul_rn(qi[4+l],  kT[(4+l)*97 + j]),
                        __fmul_rn(qi[l],    kT[(l)*97 + j]));
    t = __fadd_rn(__fmul_rn(qi[8+l],  kT[(8+l)*97 + j]), t);
    t = __fadd_rn(__fmul_rn(qi[12+l], kT[(12+l)*97 + j]), t);
    t = __fadd_rn(__fmul_rn(qi[16+l], kT[(16+l)*97 + j]), t);
    t = __fadd_rn(__fmul_rn(qi[20+l], kT[(20+l)*97 + j]), t);
    t = __fadd_rn(__fmul_rn(qi[24+l], kT[(24+l)*97 + j]), t);
    t = __fadd_rn(__fmul_rn(qi[28+l], kT[(28+l)*97 + j]), t);
    acc[l] = t;
  }
  float s01 = __fadd_rn(acc[0], acc[1]);
  float s23 = __fadd_rn(acc[2], acc[3]);
  return __fdiv_rn(__fadd_rn(s01, s23), 5.65685424949238019521f);
}

// ---- main: 2 blocks per (b,t); block owns 48 rows; msgs staged in LDS ----
// LDS ~56 KB -> 2 blocks/CU -> 4 waves/SIMD: the PROVEN spill-free point
// (R12: VGPR 72, WRITE 18.6 MB). Plain launch_bounds — every min-waves
// clause variant (R9/R10/R13/R14) made the allocator halve the arch-VGPR
// file and spill 0.25-2.7 GB to scratch.
__global__ __launch_bounds__(512) void main_kernel(
    const float* __restrict__ state, const float* __restrict__ rvec,
    const float* __restrict__ emb,
    const float* __restrict__ qwg, const float* __restrict__ qbg,
    const float* __restrict__ kwg, const float* __restrict__ kbg,
    const float* __restrict__ w1, const float* __restrict__ w2g,
    const float* __restrict__ b2g, const float* __restrict__ w3g,
    const float* __restrict__ b3g,
    const float* __restrict__ wsf,
    float* __restrict__ out_lr, float* __restrict__ out_attn){

  __shared__ __align__(16) float s_embi[HROWS*H_MLP];   // 6 KB
  __shared__ float s_embjT[H_MLP*97];                   // 12.4 KB
  __shared__ __align__(16) float s_q[HROWS*D_EMB];      // 6 KB
  __shared__ float s_kT[D_EMB*97];                      // 12.4 KB
  __shared__ float s_ms[HROWS*N_SP];                    // 18 KB
  __shared__ float s_x[N_SP], s_hol[N_SP];
  __shared__ float s_wxi[H_MLP], s_wxj[H_MLP], s_b2[H_MLP], s_w3[H_MLP];

  const int tid  = threadIdx.x;
  const int bt   = blockIdx.x >> 1;
  const int roff = (blockIdx.x & 1) * HROWS;
  const int wave = tid >> 6, lane = tid & 63;

  for (int idx = tid; idx < HROWS*H_MLP; idx += 512)
    s_embi[idx] = wsf[WS_F_EMBI + roff*H_MLP + idx];
  for (int idx = tid; idx < H_MLP*97; idx += 512)
    s_embjT[idx] = wsf[WS_F_EMBJT + idx];
  if (tid < N_SP){
    float x = state[bt*N_SP + tid];
    s_x[tid] = x;
    float al = wsf[WS_F_ALPHA + tid];
    s_hol[tid] = x / (1.f + al * x);
  }
  if (tid >= 128 && tid < 160){
    int u = tid - 128;
    s_wxi[u] = w1[u];
    s_wxj[u] = w1[H_MLP + u];
    s_b2[u]  = b2g[u];
    s_w3[u]  = w3g[u];
  }
  __syncthreads();

  // Phase 0 (bit-exact feed of scores): kT for ALL n; q for own rows.
  for (int t = tid; t < N_SP*D_EMB; t += 512){
    const int n = t >> 5, d2 = t & 31;
    const float* e = emb + n*D_EMB;
    float ak = __fmul_rn(s_x[n], kwg[d2]);
    #pragma unroll
    for (int u = 0; u < D_EMB; u++)
      ak = fmaf(e[u], kwg[(1+u)*D_EMB + d2], ak);
    ak = __fadd_rn(ak, kbg[d2]);
    s_kT[d2*97 + n] = ak;
  }
  for (int t = tid; t < HROWS*D_EMB; t += 512){
    const int nl = t >> 5, d2 = t & 31;
    const int n  = roff + nl;
    const float* e = emb + n*D_EMB;
    float aq = __fmul_rn(s_x[n], qwg[d2]);
    #pragma unroll
    for (int u = 0; u < D_EMB; u++)
      aq = fmaf(e[u], qwg[(1+u)*D_EMB + d2], aq);
    aq = __fadd_rn(aq, qbg[d2]);
    s_q[t] = aq;
  }

  const float b3v = b3g[0];
  const float* wg4 = wsf + WS_F_WG4;
  const float* wg1 = wsf + WS_F_WG1;

  // w2^T as MFMA A-operand fragments. A[row=unit l15][k=kb+e] = w2[k][unit].
  const int l15 = lane & 15;
  const int g16 = lane >> 4;
  const int kb  = g16 * 8;
  bf16x8 w2f0, w2f1;
  #pragma unroll
  for (int e = 0; e < 8; e++){
    w2f0[e] = (short)f2bf(w2g[(kb+e)*H_MLP + l15]);
    w2f1[e] = (short)f2bf(w2g[(kb+e)*H_MLP + 16 + l15]);
  }
  float b2a[4], b2b[4], w3a[4], w3b[4];
  #pragma unroll
  for (int r = 0; r < 4; r++){
    b2a[r] = s_b2[4*g16 + r];      b2b[r] = s_b2[16 + 4*g16 + r];
    w3a[r] = s_w3[4*g16 + r];      w3b[r] = s_w3[16 + 4*g16 + r];
  }
  float wi[8], wj[8];
  #pragma unroll
  for (int e = 0; e < 8; e++){ wi[e] = s_wxi[kb+e]; wj[e] = s_wxj[kb+e]; }
  __syncthreads();   // phase-0 stores visible

  // Phase 1: msgs via transposed-MFMA pairwise MLP -> LDS.
  // DUAL-ROW: wave owns 6 rows, processed in 3 pairs. The two rows share the
  // embjT LDS reads and give 2 independent MFMA/gelu/shfl chains (ILP).
  for (int ir = 0; ir < 3; ir++){
    const int ilA = 6*wave + 2*ir;       // local rows
    const int ilB = ilA + 1;
    const int iA  = roff + ilA;
    const int iB  = roff + ilB;
    const float xiA = s_x[iA];
    const float xiB = s_x[iB];
    float baseA[8], baseB[8];
    #pragma unroll
    for (int e = 0; e < 8; e++){
      baseA[e] = fmaf(xiA, wi[e], s_embi[ilA*H_MLP + kb + e]);
      baseB[e] = fmaf(xiB, wi[e], s_embi[ilB*H_MLP + kb + e]);
    }

    for (int jb = 0; jb < 6; jb++){
      const int j0 = 16*jb;
      const int jl = j0 + l15;
      const float xj = s_x[jl];

      // early loads for both rows' msg tails (hide global latency under MFMA)
      float4 w4vA = {0,0,0,0}, w4vB = {0,0,0,0};
      float  w1vA = 0.f, w1vB = 0.f, xjp = 0.f, hjp = 0.f;
      if (lane < 16){
        const int pA = iA*N_SP + j0 + lane;
        const int pB = iB*N_SP + j0 + lane;
        w4vA = *(const float4*)&wg4[4*pA];
        w1vA = wg1[pA];
        w4vB = *(const float4*)&wg4[4*pB];
        w1vB = wg1[pB];
        xjp = s_x[j0 + lane];
        hjp = s_hol[j0 + lane];
      }

      // h1 fragments (B-operand) for both rows; shared embjT reads;
      // packed bf16 conversion via v_cvt_pk_bf16_f32 (inline asm).
      u32x4 hwA, hwB;
      #pragma unroll
      for (int e2 = 0; e2 < 4; e2++){
        const float t0 = s_embjT[(kb+2*e2  )*97 + jl];
        const float t1 = s_embjT[(kb+2*e2+1)*97 + jl];
        float pA0 = gelu_fast(fmaf(xj, wj[2*e2  ], baseA[2*e2  ] + t0));
        float pA1 = gelu_fast(fmaf(xj, wj[2*e2+1], baseA[2*e2+1] + t1));
        float pB0 = gelu_fast(fmaf(xj, wj[2*e2  ], baseB[2*e2  ] + t0));
        float pB1 = gelu_fast(fmaf(xj, wj[2*e2+1], baseB[2*e2+1] + t1));
        hwA[e2] = cvt_pk_bf16(pA0, pA1);
        hwB[e2] = cvt_pk_bf16(pB0, pB1);
      }
      const bf16x8 hfA = __builtin_bit_cast(bf16x8, hwA);
      const bf16x8 hfB = __builtin_bit_cast(bf16x8, hwB);

      f32x4 a0A = {b2a[0], b2a[1], b2a[2], b2a[3]};
      f32x4 a1A = {b2b[0], b2b[1], b2b[2], b2b[3]};
      f32x4 a0B = a0A, a1B = a1A;
      a0A = __builtin_amdgcn_mfma_f32_16x16x32_bf16(w2f0, hfA, a0A, 0, 0, 0);
      a0B = __builtin_amdgcn_mfma_f32_16x16x32_bf16(w2f0, hfB, a0B, 0, 0, 0);
      a1A = __builtin_amdgcn_mfma_f32_16x16x32_bf16(w2f1, hfA, a1A, 0, 0, 0);
      a1B = __builtin_amdgcn_mfma_f32_16x16x32_bf16(w2f1, hfB, a1B, 0, 0, 0);

      float partA = 0.f, partB = 0.f;
      #pragma unroll
      for (int r = 0; r < 4; r++){
        partA = fmaf(gelu_fast(a0A[r]), w3a[r], partA);
        partB = fmaf(gelu_fast(a0B[r]), w3a[r], partB);
      }
      #pragma unroll
      for (int r = 0; r < 4; r++){
        partA = fmaf(gelu_fast(a1A[r]), w3b[r], partA);
        partB = fmaf(gelu_fast(a1B[r]), w3b[r], partB);
      }
      partA += __shfl_xor(partA, 16);
      partB += __shfl_xor(partB, 16);
      partA += __shfl_xor(partA, 32);
      partB += __shfl_xor(partB, 32);

      if (lane < 16){
        const float f4A = partA + b3v;
        const float f4B = partB + b3v;
        const float msgA = w4vA.x * xjp + w4vA.y * (xiA*xjp)
                         + w4vA.z * hjp + w4vA.w * (xiA*hjp) + w1vA * f4A;
        const float msgB = w4vB.x * xjp + w4vB.y * (xiB*xjp)
                         + w4vB.z * hjp + w4vB.w * (xiB*hjp) + w1vB * f4B;
        s_ms[ilA*N_SP + j0 + lane] = msgA;
        s_ms[ilB*N_SP + j0 + lane] = msgB;
      }
    }
  }
  __syncthreads();   // s_ms visible across waves

  // Phase 2: np-exact scores -> radix-select exact 8th-largest threshold ->
  // softmax normalized by threshold (ratio-invariant) -> aggregate.
  const float LOG2E = 1.44269504088896340736f;

  for (int ip = 0; ip < 3; ip++){
    #pragma unroll
    for (int s = 0; s < 2; s++){
      const int il2 = wave + 16*ip + 8*s;
      const int i   = roff + il2;
      const float* qi = s_q + il2*D_EMB;
      float v0 = np_score(qi, s_kT, lane);
      float v1 = 0.f;
      if (lane < 32) v1 = np_score(qi, s_kT, 64 + lane);

      unsigned k0 = __builtin_bit_cast(unsigned, v0);
      k0 = (k0 >> 31) ? ~k0 : (k0 | 0x80000000u);
      unsigned k1 = 0u;
      if (lane < 32){
        unsigned u1 = __builtin_bit_cast(unsigned, v1);
        k1 = (u1 >> 31) ? ~u1 : (u1 | 0x80000000u);
      }

      // exact 8th-largest key via 32-step binary search on bits
      unsigned T = 0u;
      #pragma unroll
      for (int b = 31; b >= 0; --b){
        unsigned Tc = T | (1u << b);
        unsigned long long mm0 = __ballot(k0 >= Tc);
        unsigned long long mm1 = __ballot(k1 >= Tc);
        int cnt = __popcll(mm0) + __popcll(mm1);
        if (cnt >= 8) T = Tc;
      }
      unsigned uth = (T >> 31) ? (T ^ 0x80000000u) : ~T;
      const float thrf = __builtin_bit_cast(float, uth);

      float e0 = (k0 >= T) ? __builtin_amdgcn_exp2f(LOG2E*(v0 - thrf)) : 0.f;
      float e1 = 0.f;
      if (lane < 32 && k1 >= T) e1 = __builtin_amdgcn_exp2f(LOG2E*(v1 - thrf));

      const float* srow = s_ms + il2*N_SP;
      float num = e0 * srow[lane];
      if (lane < 32) num += e1 * srow[64 + lane];
      float den = e0 + e1;
      #pragma unroll
      for (int off = 32; off; off >>= 1){
        den += __shfl_xor(den, off);
        num += __shfl_xor(num, off);
      }
      float inv = 1.0f / den;
      float* arow = out_attn + (size_t)(bt*N_SP + i) * N_SP;
      arow[lane] = e0 * inv;
      if (lane < 32) arow[64 + lane] = e1 * inv;
      if (lane == 0) out_lr[bt*N_SP + i] = rvec[i] + num * inv;
    }
  }
}

extern "C" void kernel_launch(void* const* d_in, const int* in_sizes, int n_in,
                              void* d_out, int out_size, void* d_ws, size_t ws_size,
                              hipStream_t stream){
  const float* state = (const float*)d_in[0];
  const float* emb   = (const float*)d_in[1];
  const float* qw    = (const float*)d_in[2];
  const float* qb    = (const float*)d_in[3];
  const float* kw    = (const float*)d_in[4];
  const float* kb    = (const float*)d_in[5];
  const float* fc    = (const float*)d_in[6];
  const float* fg    = (const float*)d_in[7];
  const float* har   = (const float*)d_in[8];
  const float* w1    = (const float*)d_in[9];
  const float* b1    = (const float*)d_in[10];
  const float* w2    = (const float*)d_in[11];
  const float* b2    = (const float*)d_in[12];
  const float* w3    = (const float*)d_in[13];
  const float* b3    = (const float*)d_in[14];
  const float* rv    = (const float*)d_in[15];

  float* wsf = (float*)d_ws;
  float* out_lr   = (float*)d_out;
  float* out_attn = out_lr + NBT * N_SP;

  hipLaunchKernelGGL(pre1_kernel, dim3(N_SP), dim3(64), 0, stream,
                     emb, w1, b1, har, wsf);
  hipLaunchKernelGGL(prewg_kernel, dim3(180), dim3(256), 0, stream, fc, fg, wsf);
  hipLaunchKernelGGL(main_kernel, dim3(2*NBT), dim3(512), 0, stream,
                     state, rv, emb, qw, qb, kw, kb, w1, w2, b2, w3, b3,
                     wsf, out_lr, out_attn);
}

// Round 17
// 108.991 us; speedup vs baseline: 2.0140x; 1.7370x over previous
//
#include <hip/hip_runtime.h>
#include <math.h>

// Problem constants
#define N_SP 96      // NV + NH
#define D_EMB 32
#define H_MLP 32
#define NPAIR 9216   // N*N
#define NBT 512      // B*T
#define HROWS 48     // rows per block (2 blocks per (b,t))

// float workspace offsets (floats)
#define WS_F_EMBI  0         // 96*32 (includes +b1)
#define WS_F_EMBJT 3072      // 32*97 (transposed [u][j], row stride 97)
#define WS_F_ALPHA 6176      // 96
#define WS_F_WG4   6272      // 9216*4  (forms 0-3, interleaved float4 per pair)
#define WS_F_WG1   43136     // 9216    (form 4 coef)

typedef __attribute__((ext_vector_type(8))) short bf16x8;
typedef __attribute__((ext_vector_type(4))) float f32x4;
typedef __attribute__((ext_vector_type(4))) unsigned u32x4;

// Fast gelu (tanh form) via v_exp_f32 + v_rcp_f32 (~3e-4 abs dev; msgs path only)
__device__ __forceinline__ float gelu_fast(float x){
  float x2 = x * x;
  float z  = x * fmaf(x2, -0.1029438824f, -2.3022077325f);
  float e  = __builtin_amdgcn_exp2f(z);
  return x * __builtin_amdgcn_rcpf(1.0f + e);
}

__device__ __forceinline__ unsigned short f2bf(float f){
  unsigned u = __builtin_bit_cast(unsigned, f);
  unsigned r = (u + 0x7FFFu + ((u >> 16) & 1u)) >> 16;
  return (unsigned short)r;
}

// packed f32x2 -> bf16x2 (RNE) in one instruction; no builtin on gfx950 (m240)
__device__ __forceinline__ unsigned cvt_pk_bf16(float lo, float hi){
  unsigned r;
  asm("v_cvt_pk_bf16_f32 %0, %1, %2" : "=v"(r) : "v"(lo), "v"(hi));
  return r;
}

// ---- precompute: emb_i(+b1), emb_jT (stride 97), alpha ----
__global__ void pre1_kernel(const float* __restrict__ emb,
                            const float* __restrict__ w1, const float* __restrict__ b1,
                            const float* __restrict__ har,
                            float* __restrict__ wsf){
  const int n = blockIdx.x;
  const int t = threadIdx.x;           // 64 threads
  const int which = t >> 5, idx = t & 31;
  const float* e = emb + n * D_EMB;
  if (which == 0){
    float acc = b1[idx];
    #pragma unroll
    for (int u = 0; u < D_EMB; u++) acc = fmaf(e[u], w1[(2+u)*H_MLP + idx], acc);
    wsf[WS_F_EMBI + n*H_MLP + idx] = acc;
  } else {
    float acc = 0.f;
    #pragma unroll
    for (int u = 0; u < D_EMB; u++) acc = fmaf(e[u], w1[(2+D_EMB+u)*H_MLP + idx], acc);
    wsf[WS_F_EMBJT + idx*97 + n] = acc;   // transposed store [u][j], stride 97
  }
  if (t == 0){
    float h = har[n];
    float sp = (h > 20.f) ? h : log1pf(expf(h));
    wsf[WS_F_ALPHA + n] = sp + 0.01f;
  }
}

// ---- precompute wg = form_coefs * sigmoid(gates), repacked ----
__global__ void prewg_kernel(const float* __restrict__ fc, const float* __restrict__ fg,
                             float* __restrict__ wsf){
  int idx = blockIdx.x * 256 + threadIdx.x;
  if (idx < 5 * NPAIR){
    float g = 1.f / (1.f + expf(-fg[idx]));
    float v = fc[idx] * g;
    int f = idx / NPAIR;
    int p = idx - f * NPAIR;
    if (f < 4) wsf[WS_F_WG4 + 4*p + f] = v;
    else       wsf[WS_F_WG1 + p] = v;
  }
}

// Emulate numpy einsum f32 dot (SSE baseline, mul+add, 4x unroll, ascending
// chain), horizontal (acc0+acc1)+(acc2+acc3), then f32 division by sqrt(32).
// DO NOT TOUCH arithmetic — bit-matched to the np reference (topk razor rows).
__device__ __forceinline__ float np_score(const float* __restrict__ qi,
                                          const float* __restrict__ kT, int j){
  float acc[4];
  #pragma unroll
  for (int l = 0; l < 4; l++){
    float t = __fadd_rn(__fmul_rn(qi[4+l],  kT[(4+l)*97 + j]),
                        __fmul_rn(qi[l],    kT[(l)*97 + j]));
    t = __fadd_rn(__fmul_rn(qi[8+l],  kT[(8+l)*97 + j]), t);
    t = __fadd_rn(__fmul_rn(qi[12+l], kT[(12+l)*97 + j]), t);
    t = __fadd_rn(__fmul_rn(qi[16+l], kT[(16+l)*97 + j]), t);
    t = __fadd_rn(__fmul_rn(qi[20+l], kT[(20+l)*97 + j]), t);
    t = __fadd_rn(__fmul_rn(qi[24+l], kT[(24+l)*97 + j]), t);
    t = __fadd_rn(__fmul_rn(qi[28+l], kT[(28+l)*97 + j]), t);
    acc[l] = t;
  }
  float s01 = __fadd_rn(acc[0], acc[1]);
  float s23 = __fadd_rn(acc[2], acc[3]);
  return __fdiv_rn(__fadd_rn(s01, s23), 5.65685424949238019521f);
}

// ---- main: 2 blocks per (b,t); block owns 48 rows. Per row: scores ->
// top-8 threshold -> compute msgs ONLY for selected pairs (one 16-pair MFMA
// batch instead of six) -> softmax -> aggregate. msgs at non-selected j
// multiply attn==0 and are never needed.
// LDS padded >53.3 KB: pins 2 blocks/CU so the allocator's occupancy
// heuristic doesn't halve the VGPR file (R13/R14: 37-41 KB -> VGPR 40 ->
// 0.25 GB scratch spill; R12/R16: ~56 KB -> VGPR 72 spill-free).
__global__ __launch_bounds__(512) void main_kernel(
    const float* __restrict__ state, const float* __restrict__ rvec,
    const float* __restrict__ emb,
    const float* __restrict__ qwg, const float* __restrict__ qbg,
    const float* __restrict__ kwg, const float* __restrict__ kbg,
    const float* __restrict__ w1, const float* __restrict__ w2g,
    const float* __restrict__ b2g, const float* __restrict__ w3g,
    const float* __restrict__ b3g,
    const float* __restrict__ wsf,
    float* __restrict__ out_lr, float* __restrict__ out_attn){

  __shared__ __align__(16) float s_embi[HROWS*H_MLP];   // 6 KB
  __shared__ float s_embjT[H_MLP*97];                   // 12.4 KB
  __shared__ __align__(16) float s_q[HROWS*D_EMB];      // 6 KB
  __shared__ float s_kT[D_EMB*97];                      // 12.4 KB
  __shared__ float s_x[N_SP], s_hol[N_SP];
  __shared__ float s_wxi[H_MLP], s_wxj[H_MLP], s_b2[H_MLP], s_w3[H_MLP];
  __shared__ int   s_selj[8][16];                       // per-wave selected j's
  __shared__ float s_msg[8][16];                        // per-wave selected msgs
  __shared__ float s_pad[3900];                         // 15.6 KB occupancy fence

  const int tid  = threadIdx.x;
  const int bt   = blockIdx.x >> 1;
  const int roff = (blockIdx.x & 1) * HROWS;
  const int wave = tid >> 6, lane = tid & 63;

  for (int idx = tid; idx < HROWS*H_MLP; idx += 512)
    s_embi[idx] = wsf[WS_F_EMBI + roff*H_MLP + idx];
  for (int idx = tid; idx < H_MLP*97; idx += 512)
    s_embjT[idx] = wsf[WS_F_EMBJT + idx];
  if (tid < N_SP){
    float x = state[bt*N_SP + tid];
    s_x[tid] = x;
    float al = wsf[WS_F_ALPHA + tid];
    s_hol[tid] = x / (1.f + al * x);
  }
  if (tid >= 128 && tid < 160){
    int u = tid - 128;
    s_wxi[u] = w1[u];
    s_wxj[u] = w1[H_MLP + u];
    s_b2[u]  = b2g[u];
    s_w3[u]  = w3g[u];
  }
  // unprovable-dead touch keeps s_pad allocated (occupancy fence)
  if (rvec[0] > 1.0e30f) s_pad[tid] = rvec[0];
  __syncthreads();

  // Phase 0 (bit-exact feed of scores): kT for ALL n; q for own rows.
  for (int t = tid; t < N_SP*D_EMB; t += 512){
    const int n = t >> 5, d2 = t & 31;
    const float* e = emb + n*D_EMB;
    float ak = __fmul_rn(s_x[n], kwg[d2]);
    #pragma unroll
    for (int u = 0; u < D_EMB; u++)
      ak = fmaf(e[u], kwg[(1+u)*D_EMB + d2], ak);
    ak = __fadd_rn(ak, kbg[d2]);
    s_kT[d2*97 + n] = ak;
  }
  for (int t = tid; t < HROWS*D_EMB; t += 512){
    const int nl = t >> 5, d2 = t & 31;
    const int n  = roff + nl;
    const float* e = emb + n*D_EMB;
    float aq = __fmul_rn(s_x[n], qwg[d2]);
    #pragma unroll
    for (int u = 0; u < D_EMB; u++)
      aq = fmaf(e[u], qwg[(1+u)*D_EMB + d2], aq);
    aq = __fadd_rn(aq, qbg[d2]);
    s_q[t] = aq;
  }

  const float b3v = b3g[0];
  const float* wg4 = wsf + WS_F_WG4;
  const float* wg1 = wsf + WS_F_WG1;

  // w2^T as MFMA A-operand fragments. A[row=unit l15][k=kb+e] = w2[k][unit].
  const int l15 = lane & 15;
  const int g16 = lane >> 4;
  const int kb  = g16 * 8;
  bf16x8 w2f0, w2f1;
  #pragma unroll
  for (int e = 0; e < 8; e++){
    w2f0[e] = (short)f2bf(w2g[(kb+e)*H_MLP + l15]);
    w2f1[e] = (short)f2bf(w2g[(kb+e)*H_MLP + 16 + l15]);
  }
  float b2a[4], b2b[4], w3a[4], w3b[4];
  #pragma unroll
  for (int r = 0; r < 4; r++){
    b2a[r] = s_b2[4*g16 + r];      b2b[r] = s_b2[16 + 4*g16 + r];
    w3a[r] = s_w3[4*g16 + r];      w3b[r] = s_w3[16 + 4*g16 + r];
  }
  float wi[8], wj[8];
  #pragma unroll
  for (int e = 0; e < 8; e++){ wi[e] = s_wxi[kb+e]; wj[e] = s_wxj[kb+e]; }
  __syncthreads();   // phase-0 stores visible; all else is wave-local

  const float LOG2E = 1.44269504088896340736f;

  // Fused per-row loop (wave owns 6 rows, no barriers):
  for (int ii = 0; ii < 6; ii++){
    const int il = 6*wave + ii;
    const int i  = roff + il;

    // ---- scores (bit-exact numpy emulation) ----
    const float* qi = s_q + il*D_EMB;
    float v0 = np_score(qi, s_kT, lane);
    float v1 = 0.f;
    if (lane < 32) v1 = np_score(qi, s_kT, 64 + lane);

    unsigned k0 = __builtin_bit_cast(unsigned, v0);
    k0 = (k0 >> 31) ? ~k0 : (k0 | 0x80000000u);
    unsigned k1 = 0u;
    if (lane < 32){
      unsigned u1 = __builtin_bit_cast(unsigned, v1);
      k1 = (u1 >> 31) ? ~u1 : (u1 | 0x80000000u);
    }

    // ---- exact 8th-largest key via 32-step binary search on bits ----
    unsigned T = 0u;
    #pragma unroll
    for (int b = 31; b >= 0; --b){
      unsigned Tc = T | (1u << b);
      unsigned long long mm0 = __ballot(k0 >= Tc);
      unsigned long long mm1 = __ballot(k1 >= Tc);
      int cnt = __popcll(mm0) + __popcll(mm1);
      if (cnt >= 8) T = Tc;
    }

    // ---- gather selected j's (>=T; ties included, matching np mask) ----
    unsigned long long mm0 = __ballot(k0 >= T);
    unsigned long long mm1 = __ballot(k1 >= T);   // k1==0 for lane>=32
    const int cnt0 = __popcll(mm0);
    const int cntT = cnt0 + __popcll(mm1);
    int r0 = -1, r1 = -1;
    if (k0 >= T){
      r0 = __popcll(mm0 & ((1ull << lane) - 1ull));
      if (r0 < 16) s_selj[wave][r0] = lane;
    }
    if (lane < 32 && k1 >= T){
      r1 = cnt0 + __popcll(mm1 & ((1ull << lane) - 1ull));
      if (r1 < 16) s_selj[wave][r1] = 64 + lane;
    }
    asm volatile("s_waitcnt lgkmcnt(0)" ::: "memory");

    const int ncap = (cntT < 16) ? cntT : 16;
    const int slot = (l15 < ncap) ? l15 : 0;
    const int jP   = s_selj[wave][slot];
    const float xj = s_x[jP];
    const float xi = s_x[i];

    // early gathered loads for the msg tail (hidden under fragment+MFMA)
    float4 w4v = {0,0,0,0};
    float  w1v = 0.f, hjp = 0.f;
    if (lane < 16){
      const int p = i*N_SP + jP;
      w4v = *(const float4*)&wg4[4*p];
      w1v = wg1[p];
      hjp = s_hol[jP];
    }

    // ---- MLP for the <=16 selected pairs: one MFMA batch ----
    float base[8];
    #pragma unroll
    for (int e = 0; e < 8; e++)
      base[e] = fmaf(xi, wi[e], s_embi[il*H_MLP + kb + e]);

    u32x4 hw;
    #pragma unroll
    for (int e2 = 0; e2 < 4; e2++){
      float p0 = gelu_fast(fmaf(xj, wj[2*e2  ], base[2*e2  ] + s_embjT[(kb+2*e2  )*97 + jP]));
      float p1 = gelu_fast(fmaf(xj, wj[2*e2+1], base[2*e2+1] + s_embjT[(kb+2*e2+1)*97 + jP]));
      hw[e2] = cvt_pk_bf16(p0, p1);
    }
    const bf16x8 hf = __builtin_bit_cast(bf16x8, hw);

    f32x4 a0 = {b2a[0], b2a[1], b2a[2], b2a[3]};
    f32x4 a1 = {b2b[0], b2b[1], b2b[2], b2b[3]};
    a0 = __builtin_amdgcn_mfma_f32_16x16x32_bf16(w2f0, hf, a0, 0, 0, 0);
    a1 = __builtin_amdgcn_mfma_f32_16x16x32_bf16(w2f1, hf, a1, 0, 0, 0);

    float part = 0.f;
    #pragma unroll
    for (int r = 0; r < 4; r++) part = fmaf(gelu_fast(a0[r]), w3a[r], part);
    #pragma unroll
    for (int r = 0; r < 4; r++) part = fmaf(gelu_fast(a1[r]), w3b[r], part);
    part += __shfl_xor(part, 16);
    part += __shfl_xor(part, 32);
    // every lane: part = f4[pair slot l15] - b3

    if (lane < 16){
      const float f4 = part + b3v;
      const float msg = w4v.x * xj
                      + w4v.y * (xi*xj)
                      + w4v.z * hjp
                      + w4v.w * (xi*hjp)
                      + w1v   * f4;
      s_msg[wave][lane] = msg;
    }
    asm volatile("s_waitcnt lgkmcnt(0)" ::: "memory");

    // ---- softmax (threshold-normalized, ratio-invariant) + aggregate ----
    unsigned uth = (T >> 31) ? (T ^ 0x80000000u) : ~T;
    const float thrf = __builtin_bit_cast(float, uth);

    float e0 = (k0 >= T) ? __builtin_amdgcn_exp2f(LOG2E*(v0 - thrf)) : 0.f;
    float e1 = 0.f;
    if (lane < 32 && k1 >= T) e1 = __builtin_amdgcn_exp2f(LOG2E*(v1 - thrf));

    float m0 = (r0 >= 0 && r0 < 16) ? s_msg[wave][r0] : 0.f;
    float m1 = (r1 >= 0 && r1 < 16) ? s_msg[wave][r1] : 0.f;

    float num = e0 * m0;
    if (lane < 32) num += e1 * m1;
    float den = e0 + e1;
    #pragma unroll
    for (int off = 32; off; off >>= 1){
      den += __shfl_xor(den, off);
      num += __shfl_xor(num, off);
    }
    float inv = 1.0f / den;
    float* arow = out_attn + (size_t)(bt*N_SP + i) * N_SP;
    arow[lane] = e0 * inv;
    if (lane < 32) arow[64 + lane] = e1 * inv;
    if (lane == 0) out_lr[bt*N_SP + i] = rvec[i] + num * inv;
  }
}

extern "C" void kernel_launch(void* const* d_in, const int* in_sizes, int n_in,
                              void* d_out, int out_size, void* d_ws, size_t ws_size,
                              hipStream_t stream){
  const float* state = (const float*)d_in[0];
  const float* emb   = (const float*)d_in[1];
  const float* qw    = (const float*)d_in[2];
  const float* qb    = (const float*)d_in[3];
  const float* kw    = (const float*)d_in[4];
  const float* kb    = (const float*)d_in[5];
  const float* fc    = (const float*)d_in[6];
  const float* fg    = (const float*)d_in[7];
  const float* har   = (const float*)d_in[8];
  const float* w1    = (const float*)d_in[9];
  const float* b1    = (const float*)d_in[10];
  const float* w2    = (const float*)d_in[11];
  const float* b2    = (const float*)d_in[12];
  const float* w3    = (const float*)d_in[13];
  const float* b3    = (const float*)d_in[14];
  const float* rv    = (const float*)d_in[15];

  float* wsf = (float*)d_ws;
  float* out_lr   = (float*)d_out;
  float* out_attn = out_lr + NBT * N_SP;

  hipLaunchKernelGGL(pre1_kernel, dim3(N_SP), dim3(64), 0, stream,
                     emb, w1, b1, har, wsf);
  hipLaunchKernelGGL(prewg_kernel, dim3(180), dim3(256), 0, stream, fc, fg, wsf);
  hipLaunchKernelGGL(main_kernel, dim3(2*NBT), dim3(512), 0, stream,
                     state, rv, emb, qw, qb, kw, kb, w1, w2, b2, w3, b3,
                     wsf, out_lr, out_attn);
}

// Round 18
// 102.218 us; speedup vs baseline: 2.1474x; 1.0663x over previous
//
#include <hip/hip_runtime.h>
#include <math.h>

// Problem constants
#define N_SP 96      // NV + NH
#define D_EMB 32
#define H_MLP 32
#define NPAIR 9216   // N*N
#define NBT 512      // B*T
#define HROWS 48     // rows per block (2 blocks per (b,t))

// float workspace offsets (floats)
#define WS_F_EMBI  0         // 96*32 (includes +b1)
#define WS_F_EMBJT 3072      // 32*97 (transposed [u][j], row stride 97)
#define WS_F_ALPHA 6176      // 96
#define WS_F_WG4   6272      // 9216*4  (forms 0-3, interleaved float4 per pair)
#define WS_F_WG1   43136     // 9216    (form 4 coef)

typedef __attribute__((ext_vector_type(8))) short bf16x8;
typedef __attribute__((ext_vector_type(4))) float f32x4;
typedef __attribute__((ext_vector_type(4))) unsigned u32x4;

// Fast gelu (tanh form) via v_exp_f32 + v_rcp_f32 (~3e-4 abs dev; msgs path only)
__device__ __forceinline__ float gelu_fast(float x){
  float x2 = x * x;
  float z  = x * fmaf(x2, -0.1029438824f, -2.3022077325f);
  float e  = __builtin_amdgcn_exp2f(z);
  return x * __builtin_amdgcn_rcpf(1.0f + e);
}

__device__ __forceinline__ unsigned short f2bf(float f){
  unsigned u = __builtin_bit_cast(unsigned, f);
  unsigned r = (u + 0x7FFFu + ((u >> 16) & 1u)) >> 16;
  return (unsigned short)r;
}

// packed f32x2 -> bf16x2 (RNE) in one instruction; no builtin on gfx950 (m240)
__device__ __forceinline__ unsigned cvt_pk_bf16(float lo, float hi){
  unsigned r;
  asm("v_cvt_pk_bf16_f32 %0, %1, %2" : "=v"(r) : "v"(lo), "v"(hi));
  return r;
}

// ---- precompute: emb_i(+b1), emb_jT (stride 97), alpha ----
__global__ void pre1_kernel(const float* __restrict__ emb,
                            const float* __restrict__ w1, const float* __restrict__ b1,
                            const float* __restrict__ har,
                            float* __restrict__ wsf){
  const int n = blockIdx.x;
  const int t = threadIdx.x;           // 64 threads
  const int which = t >> 5, idx = t & 31;
  const float* e = emb + n * D_EMB;
  if (which == 0){
    float acc = b1[idx];
    #pragma unroll
    for (int u = 0; u < D_EMB; u++) acc = fmaf(e[u], w1[(2+u)*H_MLP + idx], acc);
    wsf[WS_F_EMBI + n*H_MLP + idx] = acc;
  } else {
    float acc = 0.f;
    #pragma unroll
    for (int u = 0; u < D_EMB; u++) acc = fmaf(e[u], w1[(2+D_EMB+u)*H_MLP + idx], acc);
    wsf[WS_F_EMBJT + idx*97 + n] = acc;   // transposed store [u][j], stride 97
  }
  if (t == 0){
    float h = har[n];
    float sp = (h > 20.f) ? h : log1pf(expf(h));
    wsf[WS_F_ALPHA + n] = sp + 0.01f;
  }
}

// ---- precompute wg = form_coefs * sigmoid(gates), repacked ----
__global__ void prewg_kernel(const float* __restrict__ fc, const float* __restrict__ fg,
                             float* __restrict__ wsf){
  int idx = blockIdx.x * 256 + threadIdx.x;
  if (idx < 5 * NPAIR){
    float g = 1.f / (1.f + expf(-fg[idx]));
    float v = fc[idx] * g;
    int f = idx / NPAIR;
    int p = idx - f * NPAIR;
    if (f < 4) wsf[WS_F_WG4 + 4*p + f] = v;
    else       wsf[WS_F_WG1 + p] = v;
  }
}

// Dual-row numpy-einsum-exact score: one kT load feeds two independent
// accumulator chains. Each row's op sequence is IDENTICAL to the proven
// single np_score (SSE baseline, mul+add, 4x unroll, ascending chain,
// hadd (a0+a1)+(a2+a3), f32 divide). DO NOT TOUCH the per-row rounding.
__device__ __forceinline__ void np_score2(const float* __restrict__ qiA,
                                          const float* __restrict__ qiB,
                                          const float* __restrict__ kT, int j,
                                          float* __restrict__ vA,
                                          float* __restrict__ vB){
  float accA[4], accB[4];
  #pragma unroll
  for (int l = 0; l < 4; l++){
    const float k0 = kT[(l)*97 + j];
    const float k4 = kT[(4+l)*97 + j];
    const float k8 = kT[(8+l)*97 + j];
    const float k12 = kT[(12+l)*97 + j];
    const float k16 = kT[(16+l)*97 + j];
    const float k20 = kT[(20+l)*97 + j];
    const float k24 = kT[(24+l)*97 + j];
    const float k28 = kT[(28+l)*97 + j];
    float tA = __fadd_rn(__fmul_rn(qiA[4+l], k4), __fmul_rn(qiA[l], k0));
    float tB = __fadd_rn(__fmul_rn(qiB[4+l], k4), __fmul_rn(qiB[l], k0));
    tA = __fadd_rn(__fmul_rn(qiA[8+l],  k8),  tA);
    tB = __fadd_rn(__fmul_rn(qiB[8+l],  k8),  tB);
    tA = __fadd_rn(__fmul_rn(qiA[12+l], k12), tA);
    tB = __fadd_rn(__fmul_rn(qiB[12+l], k12), tB);
    tA = __fadd_rn(__fmul_rn(qiA[16+l], k16), tA);
    tB = __fadd_rn(__fmul_rn(qiB[16+l], k16), tB);
    tA = __fadd_rn(__fmul_rn(qiA[20+l], k20), tA);
    tB = __fadd_rn(__fmul_rn(qiB[20+l], k20), tB);
    tA = __fadd_rn(__fmul_rn(qiA[24+l], k24), tA);
    tB = __fadd_rn(__fmul_rn(qiB[24+l], k24), tB);
    tA = __fadd_rn(__fmul_rn(qiA[28+l], k28), tA);
    tB = __fadd_rn(__fmul_rn(qiB[28+l], k28), tB);
    accA[l] = tA;
    accB[l] = tB;
  }
  float sA01 = __fadd_rn(accA[0], accA[1]);
  float sA23 = __fadd_rn(accA[2], accA[3]);
  float sB01 = __fadd_rn(accB[0], accB[1]);
  float sB23 = __fadd_rn(accB[2], accB[3]);
  *vA = __fdiv_rn(__fadd_rn(sA01, sA23), 5.65685424949238019521f);
  *vB = __fdiv_rn(__fadd_rn(sB01, sB23), 5.65685424949238019521f);
}

// ---- main: 2 blocks per (b,t); block owns 48 rows. Per PAIR of rows:
// scores (dual, shared kT loads) -> dual radix top-8 -> gather selected j's
// -> one 16-pair MFMA batch per row -> msgs -> softmax -> outputs.
// 2-row interleave overlaps the serial ballot/score chains (R17: VALUBusy
// 45%, latency-bound at 5 waves/SIMD).
__global__ __launch_bounds__(512) void main_kernel(
    const float* __restrict__ state, const float* __restrict__ rvec,
    const float* __restrict__ emb,
    const float* __restrict__ qwg, const float* __restrict__ qbg,
    const float* __restrict__ kwg, const float* __restrict__ kbg,
    const float* __restrict__ w1, const float* __restrict__ w2g,
    const float* __restrict__ b2g, const float* __restrict__ w3g,
    const float* __restrict__ b3g,
    const float* __restrict__ wsf,
    float* __restrict__ out_lr, float* __restrict__ out_attn){

  __shared__ __align__(16) float s_embi[HROWS*H_MLP];   // 6 KB
  __shared__ float s_embjT[H_MLP*97];                   // 12.4 KB
  __shared__ __align__(16) float s_q[HROWS*D_EMB];      // 6 KB
  __shared__ float s_kT[D_EMB*97];                      // 12.4 KB
  __shared__ float s_x[N_SP], s_hol[N_SP];
  __shared__ float s_wxi[H_MLP], s_wxj[H_MLP], s_b2[H_MLP], s_w3[H_MLP];
  __shared__ int   s_selj[8][2][16];                    // per-wave, per-row-parity
  __shared__ float s_msg[8][2][16];

  const int tid  = threadIdx.x;
  const int bt   = blockIdx.x >> 1;
  const int roff = (blockIdx.x & 1) * HROWS;
  const int wave = tid >> 6, lane = tid & 63;

  for (int idx = tid; idx < HROWS*H_MLP; idx += 512)
    s_embi[idx] = wsf[WS_F_EMBI + roff*H_MLP + idx];
  for (int idx = tid; idx < H_MLP*97; idx += 512)
    s_embjT[idx] = wsf[WS_F_EMBJT + idx];
  if (tid < N_SP){
    float x = state[bt*N_SP + tid];
    s_x[tid] = x;
    float al = wsf[WS_F_ALPHA + tid];
    s_hol[tid] = x / (1.f + al * x);
  }
  if (tid >= 128 && tid < 160){
    int u = tid - 128;
    s_wxi[u] = w1[u];
    s_wxj[u] = w1[H_MLP + u];
    s_b2[u]  = b2g[u];
    s_w3[u]  = w3g[u];
  }
  __syncthreads();

  // Phase 0 (bit-exact feed of scores): kT for ALL n; q for own rows.
  for (int t = tid; t < N_SP*D_EMB; t += 512){
    const int n = t >> 5, d2 = t & 31;
    const float* e = emb + n*D_EMB;
    float ak = __fmul_rn(s_x[n], kwg[d2]);
    #pragma unroll
    for (int u = 0; u < D_EMB; u++)
      ak = fmaf(e[u], kwg[(1+u)*D_EMB + d2], ak);
    ak = __fadd_rn(ak, kbg[d2]);
    s_kT[d2*97 + n] = ak;
  }
  for (int t = tid; t < HROWS*D_EMB; t += 512){
    const int nl = t >> 5, d2 = t & 31;
    const int n  = roff + nl;
    const float* e = emb + n*D_EMB;
    float aq = __fmul_rn(s_x[n], qwg[d2]);
    #pragma unroll
    for (int u = 0; u < D_EMB; u++)
      aq = fmaf(e[u], qwg[(1+u)*D_EMB + d2], aq);
    aq = __fadd_rn(aq, qbg[d2]);
    s_q[t] = aq;
  }

  const float b3v = b3g[0];
  const float* wg4 = wsf + WS_F_WG4;
  const float* wg1 = wsf + WS_F_WG1;

  // w2^T as MFMA A-operand fragments. A[row=unit l15][k=kb+e] = w2[k][unit].
  const int l15 = lane & 15;
  const int g16 = lane >> 4;
  const int kb  = g16 * 8;
  bf16x8 w2f0, w2f1;
  #pragma unroll
  for (int e = 0; e < 8; e++){
    w2f0[e] = (short)f2bf(w2g[(kb+e)*H_MLP + l15]);
    w2f1[e] = (short)f2bf(w2g[(kb+e)*H_MLP + 16 + l15]);
  }
  float b2a[4], b2b[4], w3a[4], w3b[4];
  #pragma unroll
  for (int r = 0; r < 4; r++){
    b2a[r] = s_b2[4*g16 + r];      b2b[r] = s_b2[16 + 4*g16 + r];
    w3a[r] = s_w3[4*g16 + r];      w3b[r] = s_w3[16 + 4*g16 + r];
  }
  float wi[8], wj[8];
  #pragma unroll
  for (int e = 0; e < 8; e++){ wi[e] = s_wxi[kb+e]; wj[e] = s_wxj[kb+e]; }
  __syncthreads();   // phase-0 stores visible; all else is wave-local

  const float LOG2E = 1.44269504088896340736f;

  // Fused per-PAIR loop (wave owns 6 rows = 3 pairs, no barriers):
  for (int ir = 0; ir < 3; ir++){
    const int ilA = 6*wave + 2*ir, ilB = ilA + 1;
    const int iA  = roff + ilA,    iB  = roff + ilB;

    // ---- dual scores (bit-exact numpy emulation, shared kT loads) ----
    const float* qiA = s_q + ilA*D_EMB;
    const float* qiB = s_q + ilB*D_EMB;
    float v0A, v0B, v1A = 0.f, v1B = 0.f;
    np_score2(qiA, qiB, s_kT, lane, &v0A, &v0B);
    if (lane < 32) np_score2(qiA, qiB, s_kT, 64 + lane, &v1A, &v1B);

    unsigned k0A = __builtin_bit_cast(unsigned, v0A);
    k0A = (k0A >> 31) ? ~k0A : (k0A | 0x80000000u);
    unsigned k0B = __builtin_bit_cast(unsigned, v0B);
    k0B = (k0B >> 31) ? ~k0B : (k0B | 0x80000000u);
    unsigned k1A = 0u, k1B = 0u;
    if (lane < 32){
      unsigned uA = __builtin_bit_cast(unsigned, v1A);
      k1A = (uA >> 31) ? ~uA : (uA | 0x80000000u);
      unsigned uB = __builtin_bit_cast(unsigned, v1B);
      k1B = (uB >> 31) ? ~uB : (uB | 0x80000000u);
    }

    // ---- dual exact 8th-largest key (two independent serial chains) ----
    unsigned TA = 0u, TB = 0u;
    #pragma unroll
    for (int b = 31; b >= 0; --b){
      const unsigned bit = 1u << b;
      unsigned TcA = TA | bit;
      unsigned TcB = TB | bit;
      unsigned long long a0 = __ballot(k0A >= TcA);
      unsigned long long b0 = __ballot(k0B >= TcB);
      unsigned long long a1 = __ballot(k1A >= TcA);
      unsigned long long b1 = __ballot(k1B >= TcB);
      if (__popcll(a0) + __popcll(a1) >= 8) TA = TcA;
      if (__popcll(b0) + __popcll(b1) >= 8) TB = TcB;
    }

    // ---- gather selected j's for both rows ----
    unsigned long long mA0 = __ballot(k0A >= TA);
    unsigned long long mA1 = __ballot(k1A >= TA);
    unsigned long long mB0 = __ballot(k0B >= TB);
    unsigned long long mB1 = __ballot(k1B >= TB);
    const int cA0 = __popcll(mA0);
    const int cB0 = __popcll(mB0);
    int r0A = -1, r1A = -1, r0B = -1, r1B = -1;
    const unsigned long long ltm = (1ull << lane) - 1ull;
    if (k0A >= TA){
      r0A = __popcll(mA0 & ltm);
      if (r0A < 16) s_selj[wave][0][r0A] = lane;
    }
    if (lane < 32 && k1A >= TA){
      r1A = cA0 + __popcll(mA1 & ltm);
      if (r1A < 16) s_selj[wave][0][r1A] = 64 + lane;
    }
    if (k0B >= TB){
      r0B = __popcll(mB0 & ltm);
      if (r0B < 16) s_selj[wave][1][r0B] = lane;
    }
    if (lane < 32 && k1B >= TB){
      r1B = cB0 + __popcll(mB1 & ltm);
      if (r1B < 16) s_selj[wave][1][r1B] = 64 + lane;
    }
    asm volatile("s_waitcnt lgkmcnt(0)" ::: "memory");

    const int cntA = cA0 + __popcll(mA1);
    const int cntB = cB0 + __popcll(mB1);
    const int ncapA = (cntA < 16) ? cntA : 16;
    const int ncapB = (cntB < 16) ? cntB : 16;
    const int jPA = s_selj[wave][0][(l15 < ncapA) ? l15 : 0];
    const int jPB = s_selj[wave][1][(l15 < ncapB) ? l15 : 0];
    const float xjA = s_x[jPA], xjB = s_x[jPB];
    const float xiA = s_x[iA],  xiB = s_x[iB];

    // early gathered loads for both msg tails (hidden under fragments+MFMA)
    float4 w4vA = {0,0,0,0}, w4vB = {0,0,0,0};
    float  w1vA = 0.f, w1vB = 0.f, hjpA = 0.f, hjpB = 0.f;
    if (lane < 16){
      const int pA = iA*N_SP + jPA;
      const int pB = iB*N_SP + jPB;
      w4vA = *(const float4*)&wg4[4*pA];
      w1vA = wg1[pA];
      hjpA = s_hol[jPA];
      w4vB = *(const float4*)&wg4[4*pB];
      w1vB = wg1[pB];
      hjpB = s_hol[jPB];
    }

    // ---- MLP for the <=16 selected pairs of each row: 2 MFMA batches ----
    float baseA[8], baseB[8];
    #pragma unroll
    for (int e = 0; e < 8; e++){
      baseA[e] = fmaf(xiA, wi[e], s_embi[ilA*H_MLP + kb + e]);
      baseB[e] = fmaf(xiB, wi[e], s_embi[ilB*H_MLP + kb + e]);
    }

    u32x4 hwA, hwB;
    #pragma unroll
    for (int e2 = 0; e2 < 4; e2++){
      const int u0 = kb + 2*e2, u1 = u0 + 1;
      float pA0 = gelu_fast(fmaf(xjA, wj[2*e2  ], baseA[2*e2  ] + s_embjT[u0*97 + jPA]));
      float pA1 = gelu_fast(fmaf(xjA, wj[2*e2+1], baseA[2*e2+1] + s_embjT[u1*97 + jPA]));
      float pB0 = gelu_fast(fmaf(xjB, wj[2*e2  ], baseB[2*e2  ] + s_embjT[u0*97 + jPB]));
      float pB1 = gelu_fast(fmaf(xjB, wj[2*e2+1], baseB[2*e2+1] + s_embjT[u1*97 + jPB]));
      hwA[e2] = cvt_pk_bf16(pA0, pA1);
      hwB[e2] = cvt_pk_bf16(pB0, pB1);
    }
    const bf16x8 hfA = __builtin_bit_cast(bf16x8, hwA);
    const bf16x8 hfB = __builtin_bit_cast(bf16x8, hwB);

    f32x4 a0A = {b2a[0], b2a[1], b2a[2], b2a[3]};
    f32x4 a1A = {b2b[0], b2b[1], b2b[2], b2b[3]};
    f32x4 a0B = a0A, a1B = a1A;
    a0A = __builtin_amdgcn_mfma_f32_16x16x32_bf16(w2f0, hfA, a0A, 0, 0, 0);
    a0B = __builtin_amdgcn_mfma_f32_16x16x32_bf16(w2f0, hfB, a0B, 0, 0, 0);
    a1A = __builtin_amdgcn_mfma_f32_16x16x32_bf16(w2f1, hfA, a1A, 0, 0, 0);
    a1B = __builtin_amdgcn_mfma_f32_16x16x32_bf16(w2f1, hfB, a1B, 0, 0, 0);

    float partA = 0.f, partB = 0.f;
    #pragma unroll
    for (int r = 0; r < 4; r++){
      partA = fmaf(gelu_fast(a0A[r]), w3a[r], partA);
      partB = fmaf(gelu_fast(a0B[r]), w3a[r], partB);
    }
    #pragma unroll
    for (int r = 0; r < 4; r++){
      partA = fmaf(gelu_fast(a1A[r]), w3b[r], partA);
      partB = fmaf(gelu_fast(a1B[r]), w3b[r], partB);
    }
    partA += __shfl_xor(partA, 16);
    partB += __shfl_xor(partB, 16);
    partA += __shfl_xor(partA, 32);
    partB += __shfl_xor(partB, 32);

    if (lane < 16){
      const float f4A = partA + b3v;
      const float f4B = partB + b3v;
      const float msgA = w4vA.x * xjA + w4vA.y * (xiA*xjA)
                       + w4vA.z * hjpA + w4vA.w * (xiA*hjpA) + w1vA * f4A;
      const float msgB = w4vB.x * xjB + w4vB.y * (xiB*xjB)
                       + w4vB.z * hjpB + w4vB.w * (xiB*hjpB) + w1vB * f4B;
      s_msg[wave][0][lane] = msgA;
      s_msg[wave][1][lane] = msgB;
    }
    asm volatile("s_waitcnt lgkmcnt(0)" ::: "memory");

    // ---- softmax (threshold-normalized, ratio-invariant) + aggregate ----
    unsigned uthA = (TA >> 31) ? (TA ^ 0x80000000u) : ~TA;
    unsigned uthB = (TB >> 31) ? (TB ^ 0x80000000u) : ~TB;
    const float thrA = __builtin_bit_cast(float, uthA);
    const float thrB = __builtin_bit_cast(float, uthB);

    float e0A = (k0A >= TA) ? __builtin_amdgcn_exp2f(LOG2E*(v0A - thrA)) : 0.f;
    float e0B = (k0B >= TB) ? __builtin_amdgcn_exp2f(LOG2E*(v0B - thrB)) : 0.f;
    float e1A = 0.f, e1B = 0.f;
    if (lane < 32){
      if (k1A >= TA) e1A = __builtin_amdgcn_exp2f(LOG2E*(v1A - thrA));
      if (k1B >= TB) e1B = __builtin_amdgcn_exp2f(LOG2E*(v1B - thrB));
    }

    float m0A = (r0A >= 0 && r0A < 16) ? s_msg[wave][0][r0A] : 0.f;
    float m1A = (r1A >= 0 && r1A < 16) ? s_msg[wave][0][r1A] : 0.f;
    float m0B = (r0B >= 0 && r0B < 16) ? s_msg[wave][1][r0B] : 0.f;
    float m1B = (r1B >= 0 && r1B < 16) ? s_msg[wave][1][r1B] : 0.f;

    float numA = e0A * m0A;
    float numB = e0B * m0B;
    if (lane < 32){ numA += e1A * m1A; numB += e1B * m1B; }
    float denA = e0A + e1A;
    float denB = e0B + e1B;
    #pragma unroll
    for (int off = 32; off; off >>= 1){
      denA += __shfl_xor(denA, off);
      denB += __shfl_xor(denB, off);
      numA += __shfl_xor(numA, off);
      numB += __shfl_xor(numB, off);
    }
    float invA = 1.0f / denA;
    float invB = 1.0f / denB;
    float* arowA = out_attn + (size_t)(bt*N_SP + iA) * N_SP;
    float* arowB = out_attn + (size_t)(bt*N_SP + iB) * N_SP;
    arowA[lane] = e0A * invA;
    arowB[lane] = e0B * invB;
    if (lane < 32){
      arowA[64 + lane] = e1A * invA;
      arowB[64 + lane] = e1B * invB;
    }
    if (lane == 0){
      out_lr[bt*N_SP + iA] = rvec[iA] + numA * invA;
      out_lr[bt*N_SP + iB] = rvec[iB] + numB * invB;
    }
  }
}

extern "C" void kernel_launch(void* const* d_in, const int* in_sizes, int n_in,
                              void* d_out, int out_size, void* d_ws, size_t ws_size,
                              hipStream_t stream){
  const float* state = (const float*)d_in[0];
  const float* emb   = (const float*)d_in[1];
  const float* qw    = (const float*)d_in[2];
  const float* qb    = (const float*)d_in[3];
  const float* kw    = (const float*)d_in[4];
  const float* kb    = (const float*)d_in[5];
  const float* fc    = (const float*)d_in[6];
  const float* fg    = (const float*)d_in[7];
  const float* har   = (const float*)d_in[8];
  const float* w1    = (const float*)d_in[9];
  const float* b1    = (const float*)d_in[10];
  const float* w2    = (const float*)d_in[11];
  const float* b2    = (const float*)d_in[12];
  const float* w3    = (const float*)d_in[13];
  const float* b3    = (const float*)d_in[14];
  const float* rv    = (const float*)d_in[15];

  float* wsf = (float*)d_ws;
  float* out_lr   = (float*)d_out;
  float* out_attn = out_lr + NBT * N_SP;

  hipLaunchKernelGGL(pre1_kernel, dim3(N_SP), dim3(64), 0, stream,
                     emb, w1, b1, har, wsf);
  hipLaunchKernelGGL(prewg_kernel, dim3(180), dim3(256), 0, stream, fc, fg, wsf);
  hipLaunchKernelGGL(main_kernel, dim3(2*NBT), dim3(512), 0, stream,
                     state, rv, emb, qw, qb, kw, kb, w1, w2, b2, w3, b3,
                     wsf, out_lr, out_attn);
}